// Round 11
// baseline (235.264 us; speedup 1.0000x reference)
//
#include <hip/hip_runtime.h>

typedef unsigned short ushort_t;
typedef __attribute__((ext_vector_type(8))) short short8;
typedef __attribute__((ext_vector_type(4))) float floatx4;
typedef __attribute__((ext_vector_type(2))) _Float16 half2v;
typedef __attribute__((ext_vector_type(8))) _Float16 half8;

#define QSCALE 0.36067376022224085f   /* 0.25 * log2(e): fold score scale + exp->exp2 into Q */
#define SCLIP  7.2134752044448170f    /* 5 * log2(e) */

__device__ __forceinline__ unsigned h2u(half2v h) {
    union { half2v h; unsigned u; } x; x.h = h; return x.u;
}
__device__ __forceinline__ half2v u2h(unsigned u) {
    union { unsigned u; half2v h; } x; x.u = u; return x.h;
}
__device__ __forceinline__ ushort_t h2us(_Float16 h) {
    union { _Float16 h; ushort_t u; } x; x.h = h; return x.u;
}
// v_cvt_pkrtz_f16_f32: two f32 -> packed f16 (builtin returns __fp16 vector;
// bit-cast via decltype so the element-type spelling doesn't matter)
__device__ __forceinline__ unsigned pkrtz(float a, float b) {
    auto h = __builtin_amdgcn_cvt_pkrtz(a, b);
    union { decltype(h) h2; unsigned u; } x; x.h2 = h; return x.u;
}
__device__ __forceinline__ float dot2h(half2v a, half2v b, float c) {
#if __has_builtin(__builtin_amdgcn_fdot2)
    return __builtin_amdgcn_fdot2(a, b, c, false);   // v_dot2_f32_f16
#else
    return c + (float)a[0] * (float)b[0] + (float)a[1] * (float)b[1];
#endif
}
__device__ __forceinline__ half2v pk_shfl_add(half2v a, int m) {
    unsigned o = (unsigned)__shfl_xor((int)h2u(a), m, 64);
    return a + u2h(o);                               // v_pk_add_f16
}

// ------ transpose+convert weights -> f16 in MFMA B-fragment order; zero deg --
__global__ __launch_bounds__(256) void transpose_swz(
    const float* __restrict__ Wq, const float* __restrict__ Wk,
    const float* __restrict__ Wv, const float* __restrict__ Wo,
    ushort_t* __restrict__ out, int* __restrict__ deg, int* __restrict__ gcount, int N)
{
    // folded deg-memset + gcount zero (replaces hipMemsetAsync dispatch)
    int flat = (blockIdx.y * gridDim.x + blockIdx.x) * 256 + threadIdx.x;  // 0..8191
    if (flat == 0) *gcount = 0;
    for (int i = flat; i < N; i += 8192) deg[i] = 0;

    const float* W = (blockIdx.y == 0) ? Wq : (blockIdx.y == 1) ? Wk :
                     (blockIdx.y == 2) ? Wv : Wo;
    ushort_t* T = out + (size_t)blockIdx.y * 128 * 128;
    int t = blockIdx.x * 256 + threadIdx.x;   // 0..2047
    int kg = t >> 7;        // 0..15  (k-group of 8)
    int n  = t & 127;
    int k0 = kg * 8;
    float w[8];
    #pragma unroll
    for (int j = 0; j < 8; j++)
        w[j] = W[(size_t)(k0 + j) * 128 + n];
    int4 o;
    o.x = (int)pkrtz(w[0], w[1]);
    o.y = (int)pkrtz(w[2], w[3]);
    o.z = (int)pkrtz(w[4], w[5]);
    o.w = (int)pkrtz(w[6], w[7]);
    int sn = n >> 4, l15 = n & 15, kb = kg >> 2, quad = kg & 3;
    size_t f = ((size_t)((sn * 4 + kb) * 4 + quad)) * 128 + (size_t)l15 * 8;
    *(int4*)(T + f) = o;
}

// ---- QKV GEMM, MERGED (BM=32, 512 threads, 8 waves): X staged ONCE ---------
// Histogram at kernel START (r9 position): atomic latency overlaps other
// waves' X staging/MFMA. (r10's post-MFMA placement drained at the barrier.)
// KV layout: row n = [K 128 f16][V 128 f16]  (de-interleaved: full-line writes)
__global__ __launch_bounds__(512, 8) void gemm_qkv(
    const float* __restrict__ X, const ushort_t* __restrict__ Wsw,
    const float* __restrict__ bq, const float* __restrict__ bk, const float* __restrict__ bv,
    ushort_t* __restrict__ Q, ushort_t* __restrict__ KV, int M,
    const int* __restrict__ dst, int* __restrict__ deg, int* __restrict__ rank, int E)
{
    __shared__ ushort_t Xs[32 * 136];   // 8.5 KB
    __shared__ ushort_t Cs[32 * 392];   // 24.5 KB (3*128 cols + 8 pad)
    int tid = threadIdx.x;              // 0..511
    int rowBase = blockIdx.x * 32;

    // folded histogram chunk (~512 edges/block); rank = old count within dst
    {
        int nblk = gridDim.x;
        int fb = blockIdx.x;
        int per = (E + nblk - 1) / nblk;
        int end = min(per * (fb + 1), E);
        for (int i = per * fb + tid; i < end; i += 512)
            rank[i] = atomicAdd(&deg[dst[i]], 1);
    }

    // stage X: 32 rows x 16 segs of 8 cols = 512 units, 1 per thread
    {
        int r = tid >> 4;           // 0..31
        int c = (tid & 15) * 8;     // 0..120
        int row = rowBase + r;
        int rc = (row < M) ? row : (M - 1);
        const float* p = X + (size_t)rc * 128 + c;
        float4 f0 = *(const float4*)p;
        float4 f1 = *(const float4*)(p + 4);
        int4 pv;
        pv.x = (int)pkrtz(f0.x, f0.y);
        pv.y = (int)pkrtz(f0.z, f0.w);
        pv.z = (int)pkrtz(f1.x, f1.y);
        pv.w = (int)pkrtz(f1.z, f1.w);
        *(int4*)&Xs[r * 136 + c] = pv;
    }
    __syncthreads();

    int lane = tid & 63, wave = tid >> 6;   // 8 waves
    int rowT = wave & 1;                    // row-tile (16 rows)
    int mg   = wave >> 1;                   // 0..3 -> col-tiles mg*6..+5
    int l15 = lane & 15, quad = lane >> 4;
    floatx4 acc[6] = {};
    for (int kb = 0; kb < 4; kb++) {
        half8 a = *(const half8*)&Xs[(rowT * 16 + l15) * 136 + kb * 32 + quad * 8];
        #pragma unroll
        for (int s = 0; s < 6; s++) {
            int ct = mg * 6 + s;            // 0..23
            int mat = ct >> 3;              // 0..2 (Q,K,V)
            int mc  = ct & 7;               // col-tile within mat
            const ushort_t* Wmat = Wsw + (size_t)mat * 128 * 128;
            half8 b = *(const half8*)(Wmat + (size_t)(mc * 4 + kb) * 512 + lane * 8);
            acc[s] = __builtin_amdgcn_mfma_f32_16x16x32_f16(a, b, acc[s], 0, 0, 0);
        }
    }

    // stage C (f16) into Cs: wave-private region rows [rowT*16,+16), cols [mg*96,+96)
    #pragma unroll
    for (int s = 0; s < 6; s++) {
        int ct = mg * 6 + s;
        int mat = ct >> 3;
        int col = ct * 16 + l15;            // global col 0..383
        int matcol = (ct & 7) * 16 + l15;
        const float* bias = (mat == 0) ? bq : (mat == 1) ? bk : bv;
        float bia = bias[matcol];
        float scl = (mat == 0) ? QSCALE : 1.0f;
        for (int rr = 0; rr < 4; rr++) {
            int rl = rowT * 16 + quad * 4 + rr;
            Cs[rl * 392 + col] = h2us((_Float16)((acc[s][rr] + bia) * scl));
        }
    }
    __syncthreads();   // write-out crosses wave regions

    // coalesced write-out: 32 rows x 48 segs (8 cols) = 1536 units / 512 = 3 iters
    // de-interleaved KV: K at KV+row*256+mc, V at KV+row*256+128+mc
    for (int it = 0; it < 3; it++) {
        int idx = it * 512 + tid;
        int rl = idx / 48;
        int sg = idx - rl * 48;
        int row = rowBase + rl;
        if (row < M) {
            short8 v = *(const short8*)&Cs[rl * 392 + sg * 8];
            int gcol = sg * 8;              // 0..383
            int mat = gcol >> 7;
            int mc  = gcol & 127;
            if (mat == 0)
                *(short8*)(Q + (size_t)row * 128 + mc) = v;
            else
                *(short8*)(KV + (size_t)row * 256 + ((mat == 2) ? 128 : 0) + mc) = v;
        }
    }
}

// ---------------- CSR build (order-free region allocation) ----------------
__global__ __launch_bounds__(256) void k_alloc(const int* __restrict__ deg,
                                               int* __restrict__ offs, int* __restrict__ endp,
                                               int* __restrict__ gcount, int n) {
    __shared__ int s[256];
    __shared__ int base;
    int tid = threadIdx.x;
    int i = blockIdx.x * 256 + tid;
    int v = (i < n) ? deg[i] : 0;
    s[tid] = v;
    __syncthreads();
    for (int d = 1; d < 256; d <<= 1) {
        int t = (tid >= d) ? s[tid - d] : 0;
        __syncthreads();
        s[tid] += t;
        __syncthreads();
    }
    int incl = s[tid];
    if (tid == 255) base = atomicAdd(gcount, incl);   // incl@255 = block total
    __syncthreads();
    if (i < n) {
        int o = base + incl - v;
        offs[i] = o;
        endp[i] = o + v;
    }
}

// ---- atomic-free edge placement: position = offs[dst] + rank; 1 edge/thread
// (r8 form: max thread count = max outstanding scatter-writes)
__global__ __launch_bounds__(256) void k_place(const int* __restrict__ src, const int* __restrict__ dst,
                                               const int* __restrict__ rank, const int* __restrict__ offs,
                                               int* __restrict__ eadj, int E) {
    int i = blockIdx.x * 256 + threadIdx.x;
    if (i < E)
        eadj[offs[dst[i]] + rank[i]] = src[i];
}

// ---------------- edge attention + LN1 + LN2, one wave per dst node ----------
// 4x-deep gather pipeline: 16 edges (8 uint4 gathers/lane) in flight per step.
// Tail loads NOT hoisted (r5/r9/r10 evidence: hoisting costs VGPR, gains 0).
__global__ __launch_bounds__(256) void edge_attn(
    const ushort_t* __restrict__ Qb, const ushort_t* __restrict__ KV,
    const float* __restrict__ xin,
    const int* __restrict__ offs, const int* __restrict__ endp,
    const int* __restrict__ eadj,
    const float* __restrict__ g1, const float* __restrict__ be1,
    const float* __restrict__ g2, const float* __restrict__ be2,
    ushort_t* __restrict__ h1out, ushort_t* __restrict__ ln2out, int N)
{
    int wave = threadIdx.x >> 6, lane = threadIdx.x & 63;
    int n = blockIdx.x * 4 + wave;
    if (n >= N) return;
    int l15 = lane & 15, grp = lane >> 4;
    int col = l15 * 8 + grp * 2;

    // Q is pre-scaled by 0.25*log2e -> dot is directly in exp2 domain
    uint4 qp = *(const uint4*)(Qb + (size_t)n * 128 + l15 * 8);
    half2v q0 = u2h(qp.x), q1 = u2h(qp.y), q2 = u2h(qp.z), q3 = u2h(qp.w);

    int s0 = offs[n], s1 = endp[n];

    half2v a01 = u2h(0u), a23 = u2h(0u), a45 = u2h(0u), a67 = u2h(0u);
    float z = 0.f;
    for (int base = s0; base < s1; base += 64) {
        int cnt = min(s1 - base, 64);
        int ee = (base + lane < s1) ? eadj[base + lane] : 0;

        auto comp = [&](uint4 kk, uint4 vv, int jj) {
            float d = dot2h(u2h(kk.x), q0,
                      dot2h(u2h(kk.y), q1,
                      dot2h(u2h(kk.z), q2,
                      dot2h(u2h(kk.w), q3, 0.f))));
            d += __shfl_xor(d, 1, 64);                 // per-head (16-dim) dot
            float sc = fminf(SCLIP, fmaxf(-SCLIP, d));
            float e = (jj < cnt) ? exp2f(sc) : 0.f;    // native v_exp_f32 (2^x)
            _Float16 eh = (_Float16)e;
            half2v ep; ep[0] = eh; ep[1] = eh;
            a01 += u2h(vv.x) * ep;                     // v_pk_fma_f16
            a23 += u2h(vv.y) * ep;
            a45 += u2h(vv.z) * ep;
            a67 += u2h(vv.w) * ep;
            z += e;
        };

        for (int j0 = 0; j0 < cnt; j0 += 16) {
            int t0 = j0 + grp;                         // shfl idx <= 48+15 = 63
            int sn0 = __shfl(ee, t0, 64);
            int sn1 = __shfl(ee, t0 + 4, 64);
            int sn2 = __shfl(ee, t0 + 8, 64);
            int sn3 = __shfl(ee, t0 + 12, 64);
            const ushort_t* p0 = KV + (size_t)sn0 * 256 + l15 * 8;
            const ushort_t* p1 = KV + (size_t)sn1 * 256 + l15 * 8;
            const ushort_t* p2 = KV + (size_t)sn2 * 256 + l15 * 8;
            const ushort_t* p3 = KV + (size_t)sn3 * 256 + l15 * 8;
            // 8 gathers in flight before any consumption (MLP)
            uint4 kk0 = *(const uint4*)p0, vv0 = *(const uint4*)(p0 + 128);
            uint4 kk1 = *(const uint4*)p1, vv1 = *(const uint4*)(p1 + 128);
            uint4 kk2 = *(const uint4*)p2, vv2 = *(const uint4*)(p2 + 128);
            uint4 kk3 = *(const uint4*)p3, vv3 = *(const uint4*)(p3 + 128);
            comp(kk0, vv0, t0);
            comp(kk1, vv1, t0 + 4);
            comp(kk2, vv2, t0 + 8);
            comp(kk3, vv3, t0 + 12);
        }
    }
    // cross-grp reduce: packed f16 adds (4x2 lane-groups hold partial sums)
    a01 = pk_shfl_add(a01, 16); a01 = pk_shfl_add(a01, 32);
    a23 = pk_shfl_add(a23, 16); a23 = pk_shfl_add(a23, 32);
    a45 = pk_shfl_add(a45, 16); a45 = pk_shfl_add(a45, 32);
    a67 = pk_shfl_add(a67, 16); a67 = pk_shfl_add(a67, 32);
    z += __shfl_xor(z, 16, 64); z += __shfl_xor(z, 32, 64);
    float inv = 1.f / (z + 1e-3f);

    // de-dup: this lane owns cols col, col+1
    half2v ap = (grp == 0) ? a01 : (grp == 1) ? a23 : (grp == 2) ? a45 : a67;
    float a0 = (float)ap[0], a1 = (float)ap[1];

    float2 xv = *(const float2*)(xin + (size_t)n * 128 + col);
    float t0 = fmaf(a0, inv, xv.x);
    float t1 = fmaf(a1, inv, xv.y);

    float s = t0 + t1, s2 = t0 * t0 + t1 * t1;
    #pragma unroll
    for (int m = 1; m < 64; m <<= 1) { s += __shfl_xor(s, m, 64); s2 += __shfl_xor(s2, m, 64); }
    float mu = s * (1.f / 128.f);
    float var = s2 * (1.f / 128.f) - mu * mu;
    float rstd = rsqrtf(var + 1e-5f);

    float2 gv  = *(const float2*)(g1 + col);
    float2 bvv = *(const float2*)(be1 + col);
    float h0 = (t0 - mu) * rstd * gv.x + bvv.x;
    float h1 = (t1 - mu) * rstd * gv.y + bvv.y;
    *(unsigned*)(h1out + (size_t)n * 128 + col) = pkrtz(h0, h1);

    s = h0 + h1; s2 = h0 * h0 + h1 * h1;
    #pragma unroll
    for (int m = 1; m < 64; m <<= 1) { s += __shfl_xor(s, m, 64); s2 += __shfl_xor(s2, m, 64); }
    float mu2 = s * (1.f / 128.f);
    float var2 = s2 * (1.f / 128.f) - mu2 * mu2;
    float rstd2 = rsqrtf(var2 + 1e-5f);

    float2 g2v = *(const float2*)(g2 + col);
    float2 b2v = *(const float2*)(be2 + col);
    float l0 = (h0 - mu2) * rstd2 * g2v.x + b2v.x;
    float l1 = (h1 - mu2) * rstd2 * g2v.y + b2v.y;
    *(unsigned*)(ln2out + (size_t)n * 128 + col) = pkrtz(l0, l1);
}

// ---- output GEMM, MERGED (BM=32, 512 threads, 8 waves): X staged ONCE ------
// Wave w: rowT = w&1 (16 rows), col-group cg = w>>1 -> col-tiles cg*2, cg*2+1.
__global__ __launch_bounds__(512, 8) void gemm_o(
    const ushort_t* __restrict__ X, const ushort_t* __restrict__ Wsw,
    const float* __restrict__ bo, const ushort_t* __restrict__ h1in,
    float* __restrict__ Out, int M)
{
    __shared__ ushort_t Xs[32 * 136];   // 8.5 KB
    __shared__ float Cs[32 * 132];      // 16.9 KB
    int tid = threadIdx.x;              // 0..511
    int rowBase = blockIdx.x * 32;

    // stage X (ln2): 32 rows x 16 segs of 8 cols = 512 units, 1 per thread
    {
        int r = tid >> 4;
        int c = (tid & 15) * 8;
        int row = rowBase + r;
        int rc = (row < M) ? row : (M - 1);
        *(short8*)&Xs[r * 136 + c] = *(const short8*)(X + (size_t)rc * 128 + c);
    }
    __syncthreads();

    int lane = tid & 63, wave = tid >> 6;   // 8 waves
    int rowT = wave & 1;
    int cg   = wave >> 1;                   // 0..3
    int l15 = lane & 15, quad = lane >> 4;
    floatx4 acc[2] = {};
    for (int kb = 0; kb < 4; kb++) {
        half8 a = *(const half8*)&Xs[(rowT * 16 + l15) * 136 + kb * 32 + quad * 8];
        #pragma unroll
        for (int s = 0; s < 2; s++) {
            int sn = cg * 2 + s;            // 0..7
            half8 b = *(const half8*)(Wsw + (size_t)(sn * 4 + kb) * 512 + lane * 8);
            acc[s] = __builtin_amdgcn_mfma_f32_16x16x32_f16(a, b, acc[s], 0, 0, 0);
        }
    }

    // stage relu(C+bias) f32: wave-private rows [rowT*16,+16), cols [cg*32,+32)
    #pragma unroll
    for (int s = 0; s < 2; s++) {
        int cl = (cg * 2 + s) * 16 + l15;
        float bia = bo[cl];
        for (int rr = 0; rr < 4; rr++) {
            int rl = rowT * 16 + quad * 4 + rr;
            Cs[rl * 132 + cl] = fmaxf(acc[s][rr] + bia, 0.f);
        }
    }
    __syncthreads();

    // coalesced write-out: 32 rows x 32 f32x4-segs = 1024 units / 512 = 2 iters
    for (int it = 0; it < 2; it++) {
        int idx = it * 512 + tid;
        int rl = idx >> 5;                   // 0..31
        int c4 = (idx & 31) * 4;             // 0..124
        int row = rowBase + rl;
        if (row < M) {
            float4 v = *(const float4*)&Cs[rl * 132 + c4];
            uint2 hp = *(const uint2*)(h1in + (size_t)row * 128 + c4);
            half2v ha = u2h(hp.x), hb = u2h(hp.y);
            v.x += (float)ha[0];
            v.y += (float)ha[1];
            v.z += (float)hb[0];
            v.w += (float)hb[1];
            *(float4*)(Out + (size_t)row * 128 + c4) = v;
        }
    }
}

extern "C" void kernel_launch(void* const* d_in, const int* in_sizes, int n_in,
                              void* d_out, int out_size, void* d_ws, size_t ws_size,
                              hipStream_t stream) {
    const int D = 128;
    const int N = in_sizes[0] / D;
    const int E = in_sizes[1];

    const float* x   = (const float*)d_in[0];
    const int*   src = (const int*)d_in[1];
    const int*   dst = (const int*)d_in[2];
    const float* Wq  = (const float*)d_in[3];
    const float* bq  = (const float*)d_in[4];
    const float* Wk  = (const float*)d_in[5];
    const float* bk  = (const float*)d_in[6];
    const float* Wv  = (const float*)d_in[7];
    const float* bv  = (const float*)d_in[8];
    const float* Wo  = (const float*)d_in[9];
    const float* bo  = (const float*)d_in[10];
    const float* g1  = (const float*)d_in[11];
    const float* be1 = (const float*)d_in[12];
    const float* g2  = (const float*)d_in[13];
    const float* be2 = (const float*)d_in[14];

    char* ws = (char*)d_ws;
    size_t o = 0;
    auto alloc = [&](size_t b) { o = (o + 255) & ~(size_t)255; size_t r = o; o += b; return r; };
    ushort_t* Qb   = (ushort_t*)(ws + alloc((size_t)N * D * 2));
    ushort_t* KVb  = (ushort_t*)(ws + alloc((size_t)N * D * 4));   // [K 256B][V 256B] per row
    ushort_t* ln2  = (ushort_t*)(ws + alloc((size_t)N * D * 2));
    ushort_t* h1   = (ushort_t*)(ws + alloc((size_t)N * D * 2));   // f16
    ushort_t* Wt   = (ushort_t*)(ws + alloc((size_t)4 * 128 * 128 * 2));  // swizzled f16
    int*      deg  = (int*)(ws + alloc((size_t)N * 4));
    int*      offs = (int*)(ws + alloc((size_t)(N + 1) * 4));
    int*      endp = (int*)(ws + alloc((size_t)N * 4));
    int*      gcnt = (int*)(ws + alloc((size_t)256 * 4));
    int*      eadj = (int*)(ws + alloc((size_t)E * 4));
    int*      rank = (int*)(ws + alloc((size_t)E * 4));

    int nScanBlocks = (N + 255) / 256;
    int nEdgeBlocks = (E + 255) / 256;
    int nRowTiles32 = (N + 31) / 32;

    transpose_swz<<<dim3(8, 4), 256, 0, stream>>>(Wq, Wk, Wv, Wo, Wt, deg, gcnt, N);
    gemm_qkv<<<nRowTiles32, 512, 0, stream>>>(x, Wt, bq, bk, bv, Qb, KVb, N, dst, deg, rank, E);
    k_alloc<<<nScanBlocks, 256, 0, stream>>>(deg, offs, endp, gcnt, N);
    k_place<<<nEdgeBlocks, 256, 0, stream>>>(src, dst, rank, offs, eadj, E);
    edge_attn<<<(N + 3) / 4, 256, 0, stream>>>(Qb, KVb, x, offs, endp, eadj, g1, be1, g2, be2, h1, ln2, N);
    gemm_o<<<nRowTiles32, 512, 0, stream>>>(ln2, Wt + 3 * 128 * 128, bo, h1, (float*)d_out, N);
}

// Round 12
// 230.952 us; speedup vs baseline: 1.0187x; 1.0187x over previous
//
#include <hip/hip_runtime.h>

typedef unsigned short ushort_t;
typedef __attribute__((ext_vector_type(8))) short short8;
typedef __attribute__((ext_vector_type(4))) float floatx4;
typedef __attribute__((ext_vector_type(2))) _Float16 half2v;
typedef __attribute__((ext_vector_type(8))) _Float16 half8;

#define QSCALE 0.36067376022224085f   /* 0.25 * log2(e): fold score scale + exp->exp2 into Q */
#define SCLIP  7.2134752044448170f    /* 5 * log2(e) */

__device__ __forceinline__ unsigned h2u(half2v h) {
    union { half2v h; unsigned u; } x; x.h = h; return x.u;
}
__device__ __forceinline__ half2v u2h(unsigned u) {
    union { unsigned u; half2v h; } x; x.u = u; return x.h;
}
__device__ __forceinline__ ushort_t h2us(_Float16 h) {
    union { _Float16 h; ushort_t u; } x; x.h = h; return x.u;
}
// v_cvt_pkrtz_f16_f32: two f32 -> packed f16 (builtin returns __fp16 vector;
// bit-cast via decltype so the element-type spelling doesn't matter)
__device__ __forceinline__ unsigned pkrtz(float a, float b) {
    auto h = __builtin_amdgcn_cvt_pkrtz(a, b);
    union { decltype(h) h2; unsigned u; } x; x.h2 = h; return x.u;
}
__device__ __forceinline__ float dot2h(half2v a, half2v b, float c) {
#if __has_builtin(__builtin_amdgcn_fdot2)
    return __builtin_amdgcn_fdot2(a, b, c, false);   // v_dot2_f32_f16
#else
    return c + (float)a[0] * (float)b[0] + (float)a[1] * (float)b[1];
#endif
}
__device__ __forceinline__ half2v pk_shfl_add(half2v a, int m) {
    unsigned o = (unsigned)__shfl_xor((int)h2u(a), m, 64);
    return a + u2h(o);                               // v_pk_add_f16
}

// ------ transpose+convert weights -> f16 in MFMA B-fragment order; zero deg --
__global__ __launch_bounds__(256) void transpose_swz(
    const float* __restrict__ Wq, const float* __restrict__ Wk,
    const float* __restrict__ Wv, const float* __restrict__ Wo,
    ushort_t* __restrict__ out, int* __restrict__ deg, int* __restrict__ gcount, int N)
{
    // folded deg-memset + gcount zero (replaces hipMemsetAsync dispatch)
    int flat = (blockIdx.y * gridDim.x + blockIdx.x) * 256 + threadIdx.x;  // 0..8191
    if (flat == 0) *gcount = 0;
    for (int i = flat; i < N; i += 8192) deg[i] = 0;

    const float* W = (blockIdx.y == 0) ? Wq : (blockIdx.y == 1) ? Wk :
                     (blockIdx.y == 2) ? Wv : Wo;
    ushort_t* T = out + (size_t)blockIdx.y * 128 * 128;
    int t = blockIdx.x * 256 + threadIdx.x;   // 0..2047
    int kg = t >> 7;        // 0..15  (k-group of 8)
    int n  = t & 127;
    int k0 = kg * 8;
    float w[8];
    #pragma unroll
    for (int j = 0; j < 8; j++)
        w[j] = W[(size_t)(k0 + j) * 128 + n];
    int4 o;
    o.x = (int)pkrtz(w[0], w[1]);
    o.y = (int)pkrtz(w[2], w[3]);
    o.z = (int)pkrtz(w[4], w[5]);
    o.w = (int)pkrtz(w[6], w[7]);
    int sn = n >> 4, l15 = n & 15, kb = kg >> 2, quad = kg & 3;
    size_t f = ((size_t)((sn * 4 + kb) * 4 + quad)) * 128 + (size_t)l15 * 8;
    *(int4*)(T + f) = o;
}

// ---- QKV GEMM + histogram, HETEROGENEOUS blocks in one launch --------------
// Every 4th block (g%4==0, g/4<nH) is a pure-histogram block (atomic rank
// capture); the rest are pure-GEMM blocks. Both kinds co-resident -> atomic
// latency hides under other blocks' MFMA instead of serializing every block's
// head (r7-r11 structure). deg complete at kernel retire -> k_alloc safe.
// KV layout: row n = [K 128 f16][V 128 f16]  (de-interleaved: full-line writes)
__global__ __launch_bounds__(512, 8) void gemm_qkv(
    const float* __restrict__ X, const ushort_t* __restrict__ Wsw,
    const float* __restrict__ bq, const float* __restrict__ bk, const float* __restrict__ bv,
    ushort_t* __restrict__ Q, ushort_t* __restrict__ KV, int M,
    const int* __restrict__ dst, int* __restrict__ deg, int* __restrict__ rank, int E, int nH)
{
    __shared__ ushort_t Xs[32 * 136];   // 8.5 KB
    __shared__ ushort_t Cs[32 * 392];   // 24.5 KB (3*128 cols + 8 pad)
    int tid = threadIdx.x;              // 0..511
    int g = blockIdx.x;

    // histogram block?
    if ((g & 3) == 0 && (g >> 2) < nH) {
        int hid = g >> 2;
        int per = (E + nH - 1) / nH;
        int end = min(per * (hid + 1), E);
        for (int i = per * hid + tid; i < end; i += 512)
            rank[i] = atomicAdd(&deg[dst[i]], 1);
        return;
    }
    int gid = g - min((g >> 2) + 1, nH);   // dense GEMM-block index
    int rowBase = gid * 32;

    // stage X: 32 rows x 16 segs of 8 cols = 512 units, 1 per thread
    {
        int r = tid >> 4;           // 0..31
        int c = (tid & 15) * 8;     // 0..120
        int row = rowBase + r;
        int rc = (row < M) ? row : (M - 1);
        const float* p = X + (size_t)rc * 128 + c;
        float4 f0 = *(const float4*)p;
        float4 f1 = *(const float4*)(p + 4);
        int4 pv;
        pv.x = (int)pkrtz(f0.x, f0.y);
        pv.y = (int)pkrtz(f0.z, f0.w);
        pv.z = (int)pkrtz(f1.x, f1.y);
        pv.w = (int)pkrtz(f1.z, f1.w);
        *(int4*)&Xs[r * 136 + c] = pv;
    }
    __syncthreads();

    int lane = tid & 63, wave = tid >> 6;   // 8 waves
    int rowT = wave & 1;                    // row-tile (16 rows)
    int mg   = wave >> 1;                   // 0..3 -> col-tiles mg*6..+5
    int l15 = lane & 15, quad = lane >> 4;
    floatx4 acc[6] = {};
    for (int kb = 0; kb < 4; kb++) {
        half8 a = *(const half8*)&Xs[(rowT * 16 + l15) * 136 + kb * 32 + quad * 8];
        #pragma unroll
        for (int s = 0; s < 6; s++) {
            int ct = mg * 6 + s;            // 0..23
            int mat = ct >> 3;              // 0..2 (Q,K,V)
            int mc  = ct & 7;               // col-tile within mat
            const ushort_t* Wmat = Wsw + (size_t)mat * 128 * 128;
            half8 b = *(const half8*)(Wmat + (size_t)(mc * 4 + kb) * 512 + lane * 8);
            acc[s] = __builtin_amdgcn_mfma_f32_16x16x32_f16(a, b, acc[s], 0, 0, 0);
        }
    }

    // stage C (f16) into Cs: wave-private region rows [rowT*16,+16), cols [mg*96,+96)
    #pragma unroll
    for (int s = 0; s < 6; s++) {
        int ct = mg * 6 + s;
        int mat = ct >> 3;
        int col = ct * 16 + l15;            // global col 0..383
        int matcol = (ct & 7) * 16 + l15;
        const float* bias = (mat == 0) ? bq : (mat == 1) ? bk : bv;
        float bia = bias[matcol];
        float scl = (mat == 0) ? QSCALE : 1.0f;
        for (int rr = 0; rr < 4; rr++) {
            int rl = rowT * 16 + quad * 4 + rr;
            Cs[rl * 392 + col] = h2us((_Float16)((acc[s][rr] + bia) * scl));
        }
    }
    __syncthreads();   // write-out crosses wave regions

    // coalesced write-out: 32 rows x 48 segs (8 cols) = 1536 units / 512 = 3 iters
    // de-interleaved KV: K at KV+row*256+mc, V at KV+row*256+128+mc
    for (int it = 0; it < 3; it++) {
        int idx = it * 512 + tid;
        int rl = idx / 48;
        int sg = idx - rl * 48;
        int row = rowBase + rl;
        if (row < M) {
            short8 v = *(const short8*)&Cs[rl * 392 + sg * 8];
            int gcol = sg * 8;              // 0..383
            int mat = gcol >> 7;
            int mc  = gcol & 127;
            if (mat == 0)
                *(short8*)(Q + (size_t)row * 128 + mc) = v;
            else
                *(short8*)(KV + (size_t)row * 256 + ((mat == 2) ? 128 : 0) + mc) = v;
        }
    }
}

// ---------------- CSR build (order-free region allocation) ----------------
__global__ __launch_bounds__(256) void k_alloc(const int* __restrict__ deg,
                                               int* __restrict__ offs, int* __restrict__ endp,
                                               int* __restrict__ gcount, int n) {
    __shared__ int s[256];
    __shared__ int base;
    int tid = threadIdx.x;
    int i = blockIdx.x * 256 + tid;
    int v = (i < n) ? deg[i] : 0;
    s[tid] = v;
    __syncthreads();
    for (int d = 1; d < 256; d <<= 1) {
        int t = (tid >= d) ? s[tid - d] : 0;
        __syncthreads();
        s[tid] += t;
        __syncthreads();
    }
    int incl = s[tid];
    if (tid == 255) base = atomicAdd(gcount, incl);   // incl@255 = block total
    __syncthreads();
    if (i < n) {
        int o = base + incl - v;
        offs[i] = o;
        endp[i] = o + v;
    }
}

// ---- atomic-free edge placement: position = offs[dst] + rank; 1 edge/thread
__global__ __launch_bounds__(256) void k_place(const int* __restrict__ src, const int* __restrict__ dst,
                                               const int* __restrict__ rank, const int* __restrict__ offs,
                                               int* __restrict__ eadj, int E) {
    int i = blockIdx.x * 256 + threadIdx.x;
    if (i < E)
        eadj[offs[dst[i]] + rank[i]] = src[i];
}

// ---------------- edge attention + LN1 + LN2, one wave per dst node ----------
// 4x-deep gather pipeline: 16 edges (8 uint4 gathers/lane) in flight per step.
// Tail loads NOT hoisted (r5/r9/r10 evidence: hoisting costs VGPR, gains 0).
__global__ __launch_bounds__(256) void edge_attn(
    const ushort_t* __restrict__ Qb, const ushort_t* __restrict__ KV,
    const float* __restrict__ xin,
    const int* __restrict__ offs, const int* __restrict__ endp,
    const int* __restrict__ eadj,
    const float* __restrict__ g1, const float* __restrict__ be1,
    const float* __restrict__ g2, const float* __restrict__ be2,
    ushort_t* __restrict__ h1out, ushort_t* __restrict__ ln2out, int N)
{
    int wave = threadIdx.x >> 6, lane = threadIdx.x & 63;
    int n = blockIdx.x * 4 + wave;
    if (n >= N) return;
    int l15 = lane & 15, grp = lane >> 4;
    int col = l15 * 8 + grp * 2;

    // Q is pre-scaled by 0.25*log2e -> dot is directly in exp2 domain
    uint4 qp = *(const uint4*)(Qb + (size_t)n * 128 + l15 * 8);
    half2v q0 = u2h(qp.x), q1 = u2h(qp.y), q2 = u2h(qp.z), q3 = u2h(qp.w);

    int s0 = offs[n], s1 = endp[n];

    half2v a01 = u2h(0u), a23 = u2h(0u), a45 = u2h(0u), a67 = u2h(0u);
    float z = 0.f;
    for (int base = s0; base < s1; base += 64) {
        int cnt = min(s1 - base, 64);
        int ee = (base + lane < s1) ? eadj[base + lane] : 0;

        auto comp = [&](uint4 kk, uint4 vv, int jj) {
            float d = dot2h(u2h(kk.x), q0,
                      dot2h(u2h(kk.y), q1,
                      dot2h(u2h(kk.z), q2,
                      dot2h(u2h(kk.w), q3, 0.f))));
            d += __shfl_xor(d, 1, 64);                 // per-head (16-dim) dot
            float sc = fminf(SCLIP, fmaxf(-SCLIP, d));
            float e = (jj < cnt) ? exp2f(sc) : 0.f;    // native v_exp_f32 (2^x)
            _Float16 eh = (_Float16)e;
            half2v ep; ep[0] = eh; ep[1] = eh;
            a01 += u2h(vv.x) * ep;                     // v_pk_fma_f16
            a23 += u2h(vv.y) * ep;
            a45 += u2h(vv.z) * ep;
            a67 += u2h(vv.w) * ep;
            z += e;
        };

        for (int j0 = 0; j0 < cnt; j0 += 16) {
            int t0 = j0 + grp;                         // shfl idx <= 48+15 = 63
            int sn0 = __shfl(ee, t0, 64);
            int sn1 = __shfl(ee, t0 + 4, 64);
            int sn2 = __shfl(ee, t0 + 8, 64);
            int sn3 = __shfl(ee, t0 + 12, 64);
            const ushort_t* p0 = KV + (size_t)sn0 * 256 + l15 * 8;
            const ushort_t* p1 = KV + (size_t)sn1 * 256 + l15 * 8;
            const ushort_t* p2 = KV + (size_t)sn2 * 256 + l15 * 8;
            const ushort_t* p3 = KV + (size_t)sn3 * 256 + l15 * 8;
            // 8 gathers in flight before any consumption (MLP)
            uint4 kk0 = *(const uint4*)p0, vv0 = *(const uint4*)(p0 + 128);
            uint4 kk1 = *(const uint4*)p1, vv1 = *(const uint4*)(p1 + 128);
            uint4 kk2 = *(const uint4*)p2, vv2 = *(const uint4*)(p2 + 128);
            uint4 kk3 = *(const uint4*)p3, vv3 = *(const uint4*)(p3 + 128);
            comp(kk0, vv0, t0);
            comp(kk1, vv1, t0 + 4);
            comp(kk2, vv2, t0 + 8);
            comp(kk3, vv3, t0 + 12);
        }
    }
    // cross-grp reduce: packed f16 adds (4x2 lane-groups hold partial sums)
    a01 = pk_shfl_add(a01, 16); a01 = pk_shfl_add(a01, 32);
    a23 = pk_shfl_add(a23, 16); a23 = pk_shfl_add(a23, 32);
    a45 = pk_shfl_add(a45, 16); a45 = pk_shfl_add(a45, 32);
    a67 = pk_shfl_add(a67, 16); a67 = pk_shfl_add(a67, 32);
    z += __shfl_xor(z, 16, 64); z += __shfl_xor(z, 32, 64);
    float inv = 1.f / (z + 1e-3f);

    // de-dup: this lane owns cols col, col+1
    half2v ap = (grp == 0) ? a01 : (grp == 1) ? a23 : (grp == 2) ? a45 : a67;
    float a0 = (float)ap[0], a1 = (float)ap[1];

    float2 xv = *(const float2*)(xin + (size_t)n * 128 + col);
    float t0 = fmaf(a0, inv, xv.x);
    float t1 = fmaf(a1, inv, xv.y);

    float s = t0 + t1, s2 = t0 * t0 + t1 * t1;
    #pragma unroll
    for (int m = 1; m < 64; m <<= 1) { s += __shfl_xor(s, m, 64); s2 += __shfl_xor(s2, m, 64); }
    float mu = s * (1.f / 128.f);
    float var = s2 * (1.f / 128.f) - mu * mu;
    float rstd = rsqrtf(var + 1e-5f);

    float2 gv  = *(const float2*)(g1 + col);
    float2 bvv = *(const float2*)(be1 + col);
    float h0 = (t0 - mu) * rstd * gv.x + bvv.x;
    float h1 = (t1 - mu) * rstd * gv.y + bvv.y;
    *(unsigned*)(h1out + (size_t)n * 128 + col) = pkrtz(h0, h1);

    s = h0 + h1; s2 = h0 * h0 + h1 * h1;
    #pragma unroll
    for (int m = 1; m < 64; m <<= 1) { s += __shfl_xor(s, m, 64); s2 += __shfl_xor(s2, m, 64); }
    float mu2 = s * (1.f / 128.f);
    float var2 = s2 * (1.f / 128.f) - mu2 * mu2;
    float rstd2 = rsqrtf(var2 + 1e-5f);

    float2 g2v = *(const float2*)(g2 + col);
    float2 b2v = *(const float2*)(be2 + col);
    float l0 = (h0 - mu2) * rstd2 * g2v.x + b2v.x;
    float l1 = (h1 - mu2) * rstd2 * g2v.y + b2v.y;
    *(unsigned*)(ln2out + (size_t)n * 128 + col) = pkrtz(l0, l1);
}

// ---- output GEMM, MERGED (BM=32, 512 threads, 8 waves): X staged ONCE ------
// Wave w: rowT = w&1 (16 rows), col-group cg = w>>1 -> col-tiles cg*2, cg*2+1.
__global__ __launch_bounds__(512, 8) void gemm_o(
    const ushort_t* __restrict__ X, const ushort_t* __restrict__ Wsw,
    const float* __restrict__ bo, const ushort_t* __restrict__ h1in,
    float* __restrict__ Out, int M)
{
    __shared__ ushort_t Xs[32 * 136];   // 8.5 KB
    __shared__ float Cs[32 * 132];      // 16.9 KB
    int tid = threadIdx.x;              // 0..511
    int rowBase = blockIdx.x * 32;

    // stage X (ln2): 32 rows x 16 segs of 8 cols = 512 units, 1 per thread
    {
        int r = tid >> 4;
        int c = (tid & 15) * 8;
        int row = rowBase + r;
        int rc = (row < M) ? row : (M - 1);
        *(short8*)&Xs[r * 136 + c] = *(const short8*)(X + (size_t)rc * 128 + c);
    }
    __syncthreads();

    int lane = tid & 63, wave = tid >> 6;   // 8 waves
    int rowT = wave & 1;
    int cg   = wave >> 1;                   // 0..3
    int l15 = lane & 15, quad = lane >> 4;
    floatx4 acc[2] = {};
    for (int kb = 0; kb < 4; kb++) {
        half8 a = *(const half8*)&Xs[(rowT * 16 + l15) * 136 + kb * 32 + quad * 8];
        #pragma unroll
        for (int s = 0; s < 2; s++) {
            int sn = cg * 2 + s;            // 0..7
            half8 b = *(const half8*)(Wsw + (size_t)(sn * 4 + kb) * 512 + lane * 8);
            acc[s] = __builtin_amdgcn_mfma_f32_16x16x32_f16(a, b, acc[s], 0, 0, 0);
        }
    }

    // stage relu(C+bias) f32: wave-private rows [rowT*16,+16), cols [cg*32,+32)
    #pragma unroll
    for (int s = 0; s < 2; s++) {
        int cl = (cg * 2 + s) * 16 + l15;
        float bia = bo[cl];
        for (int rr = 0; rr < 4; rr++) {
            int rl = rowT * 16 + quad * 4 + rr;
            Cs[rl * 132 + cl] = fmaxf(acc[s][rr] + bia, 0.f);
        }
    }
    __syncthreads();

    // coalesced write-out: 32 rows x 32 f32x4-segs = 1024 units / 512 = 2 iters
    for (int it = 0; it < 2; it++) {
        int idx = it * 512 + tid;
        int rl = idx >> 5;                   // 0..31
        int c4 = (idx & 31) * 4;             // 0..124
        int row = rowBase + rl;
        if (row < M) {
            float4 v = *(const float4*)&Cs[rl * 132 + c4];
            uint2 hp = *(const uint2*)(h1in + (size_t)row * 128 + c4);
            half2v ha = u2h(hp.x), hb = u2h(hp.y);
            v.x += (float)ha[0];
            v.y += (float)ha[1];
            v.z += (float)hb[0];
            v.w += (float)hb[1];
            *(float4*)(Out + (size_t)row * 128 + c4) = v;
        }
    }
}

extern "C" void kernel_launch(void* const* d_in, const int* in_sizes, int n_in,
                              void* d_out, int out_size, void* d_ws, size_t ws_size,
                              hipStream_t stream) {
    const int D = 128;
    const int N = in_sizes[0] / D;
    const int E = in_sizes[1];

    const float* x   = (const float*)d_in[0];
    const int*   src = (const int*)d_in[1];
    const int*   dst = (const int*)d_in[2];
    const float* Wq  = (const float*)d_in[3];
    const float* bq  = (const float*)d_in[4];
    const float* Wk  = (const float*)d_in[5];
    const float* bk  = (const float*)d_in[6];
    const float* Wv  = (const float*)d_in[7];
    const float* bv  = (const float*)d_in[8];
    const float* Wo  = (const float*)d_in[9];
    const float* bo  = (const float*)d_in[10];
    const float* g1  = (const float*)d_in[11];
    const float* be1 = (const float*)d_in[12];
    const float* g2  = (const float*)d_in[13];
    const float* be2 = (const float*)d_in[14];

    char* ws = (char*)d_ws;
    size_t o = 0;
    auto alloc = [&](size_t b) { o = (o + 255) & ~(size_t)255; size_t r = o; o += b; return r; };
    ushort_t* Qb   = (ushort_t*)(ws + alloc((size_t)N * D * 2));
    ushort_t* KVb  = (ushort_t*)(ws + alloc((size_t)N * D * 4));   // [K 256B][V 256B] per row
    ushort_t* ln2  = (ushort_t*)(ws + alloc((size_t)N * D * 2));
    ushort_t* h1   = (ushort_t*)(ws + alloc((size_t)N * D * 2));   // f16
    ushort_t* Wt   = (ushort_t*)(ws + alloc((size_t)4 * 128 * 128 * 2));  // swizzled f16
    int*      deg  = (int*)(ws + alloc((size_t)N * 4));
    int*      offs = (int*)(ws + alloc((size_t)(N + 1) * 4));
    int*      endp = (int*)(ws + alloc((size_t)N * 4));
    int*      gcnt = (int*)(ws + alloc((size_t)256 * 4));
    int*      eadj = (int*)(ws + alloc((size_t)E * 4));
    int*      rank = (int*)(ws + alloc((size_t)E * 4));

    int nScanBlocks = (N + 255) / 256;
    int nEdgeBlocks = (E + 255) / 256;
    int nRowTiles32 = (N + 31) / 32;
    int nH = 512;   // histogram blocks interleaved into gemm_qkv's grid

    transpose_swz<<<dim3(8, 4), 256, 0, stream>>>(Wq, Wk, Wv, Wo, Wt, deg, gcnt, N);
    gemm_qkv<<<nRowTiles32 + nH, 512, 0, stream>>>(x, Wt, bq, bk, bv, Qb, KVb, N, dst, deg, rank, E, nH);
    k_alloc<<<nScanBlocks, 256, 0, stream>>>(deg, offs, endp, gcnt, N);
    k_place<<<nEdgeBlocks, 256, 0, stream>>>(src, dst, rank, offs, eadj, E);
    edge_attn<<<(N + 3) / 4, 256, 0, stream>>>(Qb, KVb, x, offs, endp, eadj, g1, be1, g2, be2, h1, ln2, N);
    gemm_o<<<nRowTiles32, 512, 0, stream>>>(ln2, Wt + 3 * 128 * 128, bo, h1, (float*)d_out, N);
}